// Round 10
// baseline (431.555 us; speedup 1.0000x reference)
//
#include <hip/hip_runtime.h>
#include <hip/hip_bf16.h>

#define B_ 4
#define L_ 3136
#define D_ 256
#define NCH 49     // 49 chunks * 64 = 3136
#define LCH 64
#define M_ (B_*L_)

__device__ __forceinline__ float bf2f(unsigned short u) {
    union { unsigned int i; float f; } v; v.i = ((unsigned int)u) << 16; return v.f;
}
__device__ __forceinline__ unsigned short f2bs(float f) {
    __hip_bfloat16 h = __float2bfloat16(f);
    return *(unsigned short*)&h;
}
// dual-dtype load for INPUT tensors (bf16 if flag, else fp32)
__device__ __forceinline__ float ldw(const void* p, size_t i, bool bf) {
    return bf ? bf2f(((const unsigned short*)p)[i]) : ((const float*)p)[i];
}
__device__ __forceinline__ void cvt4(ushort4 a, float* o) {
    o[0] = bf2f(a.x); o[1] = bf2f(a.y); o[2] = bf2f(a.z); o[3] = bf2f(a.w);
}
__device__ __forceinline__ void cvt8g(const unsigned short* p, bool v, float* o) {
    if (v) {
        ushort4 a = *(const ushort4*)p;
        ushort4 b = *(const ushort4*)(p + 4);
        cvt4(a, o); cvt4(b, o + 4);
    } else {
        #pragma unroll
        for (int i = 0; i < 8; ++i) o[i] = 0.f;
    }
}
// DPP cross-lane adds within quads (xor1 / xor2) -- pure VALU, no LDS pipe
__device__ __forceinline__ float dpp_add_xor1(float x) {
    int m = __builtin_amdgcn_update_dpp(0, __float_as_int(x), 0xB1, 0xF, 0xF, true);
    return x + __int_as_float(m);
}
__device__ __forceinline__ float dpp_add_xor2(float x) {
    int m = __builtin_amdgcn_update_dpp(0, __float_as_int(x), 0x4E, 0xF, 0xF, true);
    return x + __int_as_float(m);
}

// ------------------------------------------------- dtype detection
__global__ __launch_bounds__(256) void detect_kernel(
    const unsigned int* __restrict__ xw, int* __restrict__ flag)
{
    int t = threadIdx.x; int cnt = 0;
    for (int i = t; i < 2048; i += 256) {
        unsigned int lo = xw[i] & 0xFFFFu;
        unsigned int e = (lo >> 7) & 0xFFu;
        if (e >= 0x58u && e <= 0x97u) cnt++;
    }
    #pragma unroll
    for (int o = 32; o > 0; o >>= 1) cnt += __shfl_down(cnt, o);
    __shared__ int sred[4];
    if ((t & 63) == 0) sred[t >> 6] = cnt;
    __syncthreads();
    if (t == 0) flag[0] = (sred[0] + sred[1] + sred[2] + sred[3] > 1024) ? 1 : 0;
}

// ------------------------------------------------- LayerNorm (1 wave = 1 row, 4 elem/thread)
__global__ __launch_bounds__(256) void ln_kernel(
    const void* __restrict__ xin, int inmode,   // -1: dual via flag; 1: bf16
    const void* __restrict__ g, const void* __restrict__ bsh,
    unsigned short* __restrict__ out, const int* __restrict__ flagp)
{
    const bool wbf = (*flagp != 0);
    const bool inbf = (inmode < 0) ? wbf : true;
    int row = blockIdx.x * 4 + (threadIdx.x >> 6);
    int lane = threadIdx.x & 63;
    size_t idx = (size_t)row * 256 + lane * 4;
    float v[4];
    if (inbf) {
        ushort4 a = *(const ushort4*)((const unsigned short*)xin + idx);
        cvt4(a, v);
    } else {
        float4 a = *(const float4*)((const float*)xin + idx);
        v[0] = a.x; v[1] = a.y; v[2] = a.z; v[3] = a.w;
    }
    float s = v[0] + v[1] + v[2] + v[3];
    float s2 = v[0]*v[0] + v[1]*v[1] + v[2]*v[2] + v[3]*v[3];
    #pragma unroll
    for (int o = 32; o > 0; o >>= 1) { s += __shfl_xor(s, o); s2 += __shfl_xor(s2, o); }
    float mean = s * (1.f / 256.f);
    float var  = s2 * (1.f / 256.f) - mean * mean;
    float rs = rsqrtf(var + 1e-5f);
    ushort4 o;
    o.x = f2bs((v[0] - mean) * rs * ldw(g, lane*4+0, wbf) + ldw(bsh, lane*4+0, wbf));
    o.y = f2bs((v[1] - mean) * rs * ldw(g, lane*4+1, wbf) + ldw(bsh, lane*4+1, wbf));
    o.z = f2bs((v[2] - mean) * rs * ldw(g, lane*4+2, wbf) + ldw(bsh, lane*4+2, wbf));
    o.w = f2bs((v[3] - mean) * rs * ldw(g, lane*4+3, wbf) + ldw(bsh, lane*4+3, wbf));
    *(ushort4*)(out + idx) = o;
}

// ------------------------------------------------- epilogue tags
enum { EPI_NONE = 0, EPI_SP = 1, EPI_RES = 2, EPI_GELU = 3, EPI_OUT = 4 };

typedef __attribute__((ext_vector_type(8))) short bf16x8;
typedef __attribute__((ext_vector_type(4))) float f32x4;

__device__ __forceinline__ void gload_lds16(const void* g, void* l) {
    __builtin_amdgcn_global_load_lds(
        (const __attribute__((address_space(1))) unsigned int*)g,
        (__attribute__((address_space(3))) unsigned int*)l, 16, 0, 0);
}

// ------------------------------------------------- MFMA bf16 GEMM
// 64 x (64*NB) tile, BK=64, 3-buffer depth-2 counted-vmcnt pipeline (wbf path).
template<int EPI, int NB>
__global__ __launch_bounds__(256) void mgemm_kernel(
    const unsigned short* __restrict__ A, const unsigned short* __restrict__ A2, int Ksplit,
    const void* __restrict__ W, void* __restrict__ Cout,
    int N, int K, int lda, int ldc,
    const void* __restrict__ bias, const void* __restrict__ resb,
    const unsigned short* __restrict__ resf, const int* __restrict__ flagp)
{
    const bool wbf = (*flagp != 0);
    constexpr int BN = 64 * NB;
    constexpr int J  = 2 * NB;     // 16-col frags per wave
    __shared__ unsigned short As[3][64][64];
    __shared__ unsigned short Ws[3][BN][64];
    const int tid = threadIdx.x;

    const int nwg = gridDim.x * gridDim.y;
    int bid = blockIdx.y * gridDim.x + blockIdx.x;
    int wgid = ((nwg & 7) == 0) ? ((bid & 7) * (nwg >> 3) + (bid >> 3)) : bid;
    const int bx = wgid % gridDim.x;
    const int by = wgid / gridDim.x;
    const int bm = by * 64, bn = bx * BN;

    const int l = tid & 63, wid = tid >> 6;
    const int wr = wid >> 1, wc = wid & 1;   // wave: 32 rows x (32*NB) cols
    const int lr = l & 15;
    const int lq = l >> 4;
    const int srow = tid >> 3;
    const int sblk = ((tid & 7) ^ (srow & 7)) * 8;
    const int dcol = (tid & 7) * 8;

    f32x4 acc[2][J] = {};
    const int NT = K >> 6;

    auto stage = [&](int buf, int k0s) {
        const unsigned short* Ab; int kc;
        if (k0s < Ksplit) { Ab = A;  kc = k0s; }
        else              { Ab = A2; kc = k0s - Ksplit; }
        gload_lds16(Ab + (size_t)(bm + srow) * lda + kc + sblk,      &As[buf][srow][dcol]);
        gload_lds16(Ab + (size_t)(bm + 32 + srow) * lda + kc + sblk, &As[buf][32 + srow][dcol]);
        if (wbf) {
            const unsigned short* Wb = (const unsigned short*)W;
            #pragma unroll
            for (int h = 0; h < 2 * NB; ++h)
                gload_lds16(Wb + (size_t)(bn + h * 32 + srow) * K + k0s + sblk,
                            &Ws[buf][h * 32 + srow][dcol]);
        } else {
            const float* Wf = (const float*)W;
            #pragma unroll
            for (int h = 0; h < 2 * NB; ++h) {
                int row = h * 32 + srow;
                const float* p = Wf + (size_t)(bn + row) * K + k0s + (tid & 7) * 8;
                float4 w0 = *(const float4*)p;
                float4 w1 = *(const float4*)(p + 4);
                ushort4 o0, o1;
                o0.x = f2bs(w0.x); o0.y = f2bs(w0.y); o0.z = f2bs(w0.z); o0.w = f2bs(w0.w);
                o1.x = f2bs(w1.x); o1.y = f2bs(w1.y); o1.z = f2bs(w1.z); o1.w = f2bs(w1.w);
                *(ushort4*)&Ws[buf][row][sblk]     = o0;
                *(ushort4*)&Ws[buf][row][sblk + 4] = o1;
            }
        }
    };

    auto compute = [&](int buf) {
        bf16x8 af[2][2], bfr[J][2];
        #pragma unroll
        for (int i = 0; i < 2; ++i)
            #pragma unroll
            for (int ks = 0; ks < 2; ++ks) {
                int ca = ((ks * 4 + lq) ^ (lr & 7)) * 8;
                af[i][ks] = *(const bf16x8*)&As[buf][wr * 32 + i * 16 + lr][ca];
            }
        #pragma unroll
        for (int j = 0; j < J; ++j)
            #pragma unroll
            for (int ks = 0; ks < 2; ++ks) {
                int ca = ((ks * 4 + lq) ^ (lr & 7)) * 8;
                bfr[j][ks] = *(const bf16x8*)&Ws[buf][wc * (32 * NB) + j * 16 + lr][ca];
            }
        #pragma unroll
        for (int ks = 0; ks < 2; ++ks)
            #pragma unroll
            for (int i = 0; i < 2; ++i)
                #pragma unroll
                for (int j = 0; j < J; ++j)
                    acc[i][j] = __builtin_amdgcn_mfma_f32_16x16x32_bf16(af[i][ks], bfr[j][ks], acc[i][j], 0, 0, 0);
    };

    // per-stage in-flight vmem loads (wbf): 2 A + 2*NB W
    #define WAIT_LPS() do { \
        if constexpr (NB == 1) asm volatile("s_waitcnt vmcnt(4)" ::: "memory"); \
        else                   asm volatile("s_waitcnt vmcnt(6)" ::: "memory"); } while (0)

    if (wbf) {
        stage(0, 0);
        if (NT > 1) { stage(1, 64); WAIT_LPS(); }
        else        { asm volatile("s_waitcnt vmcnt(0)" ::: "memory"); }
        __builtin_amdgcn_s_barrier();
        for (int kt = 0; kt < NT; ++kt) {
            if (kt + 2 < NT) stage((kt + 2) % 3, (kt + 2) << 6);
            compute(kt % 3);
            if (kt + 1 < NT) {
                if (kt + 2 < NT) { WAIT_LPS(); }
                else             { asm volatile("s_waitcnt vmcnt(0)" ::: "memory"); }
                __builtin_amdgcn_s_barrier();
            }
        }
    } else {
        stage(0, 0);
        __syncthreads();
        for (int kt = 0; kt < NT; ++kt) {
            if (kt + 1 < NT) stage((kt + 1) % 3, (kt + 1) << 6);
            compute(kt % 3);
            if (kt + 1 < NT) __syncthreads();
        }
    }
    #undef WAIT_LPS

    #pragma unroll
    for (int i = 0; i < 2; ++i) {
        #pragma unroll
        for (int j = 0; j < J; ++j) {
            const int col = bn + wc * (32 * NB) + j * 16 + lr;
            #pragma unroll
            for (int e = 0; e < 4; ++e) {
                const int row = bm + wr * 32 + i * 16 + lq * 4 + e;
                float t = acc[i][j][e];
                if (EPI == EPI_RES) {
                    t += ldw(resb, (size_t)row * 256 + col, wbf);
                } else if (EPI == EPI_GELU) {
                    t += ldw(bias, col, wbf);
                    t = 0.5f * t * (1.f + erff(t * 0.70710678118654752f));
                } else if (EPI == EPI_OUT) {
                    t += ldw(bias, col, wbf) + bf2f(resf[(size_t)row * 256 + col]);
                }
                if (EPI == EPI_OUT && !wbf) {
                    ((float*)Cout)[(size_t)row * ldc + col] = t;
                } else {
                    ((unsigned short*)Cout)[(size_t)row * ldc + col] = f2bs(t);
                }
            }
        }
    }
}

// ------------------------------------------------- fused x_proj + dt_proj + softplus
__global__ __launch_bounds__(256) void xdt_kernel(
    const unsigned short* __restrict__ A, const void* __restrict__ Wx,
    const void* __restrict__ Wd, float* __restrict__ xdbl,
    unsigned short* __restrict__ delta, const void* __restrict__ bias,
    const int* __restrict__ flagp)
{
    const bool wbf = (*flagp != 0);
    __shared__ unsigned short As[2][64][64];
    __shared__ unsigned short Ws[2][64][64];
    __shared__ unsigned short Ahl[64][40];   // cols 0-15 hi, 16-31 lo (padded)
    const int tid = threadIdx.x;
    const int bm = blockIdx.y * 64;   // gridDim.x == 1

    const int l = tid & 63, wid = tid >> 6;
    const int wr = wid >> 1, wc = wid & 1;
    const int lr = l & 15, lq = l >> 4;
    const int srow = tid >> 3;
    const int sblk = ((tid & 7) ^ (srow & 7)) * 8;
    const int dcol = (tid & 7) * 8;

    {   // zero Wx rows 48..63 of both buffers
        ushort4 zz4; zz4.x = 0; zz4.y = 0; zz4.z = 0; zz4.w = 0;
        int buf = tid >> 7, rr = 48 + ((tid >> 3) & 15), cc = (tid & 7) * 8;
        *(ushort4*)&Ws[buf][rr][cc] = zz4;
        *(ushort4*)&Ws[buf][rr][cc + 4] = zz4;
    }
    __syncthreads();

    f32x4 acc[2][2] = {};

    auto stage = [&](int buf, int k0s) {
        gload_lds16(A + (size_t)(bm + srow) * 256 + k0s + sblk,      &As[buf][srow][dcol]);
        gload_lds16(A + (size_t)(bm + 32 + srow) * 256 + k0s + sblk, &As[buf][32 + srow][dcol]);
        if (wbf) {
            const unsigned short* Wb = (const unsigned short*)Wx;
            gload_lds16(Wb + (size_t)srow * 256 + k0s + sblk, &Ws[buf][srow][dcol]);
            if (srow < 16)
                gload_lds16(Wb + (size_t)(32 + srow) * 256 + k0s + sblk, &Ws[buf][32 + srow][dcol]);
        } else {
            const float* Wf = (const float*)Wx;
            #pragma unroll
            for (int h = 0; h < 2; ++h) {
                int row = h * 32 + srow;
                if (row < 48) {
                    const float* p = Wf + (size_t)row * 256 + k0s + (tid & 7) * 8;
                    float4 w0 = *(const float4*)p;
                    float4 w1 = *(const float4*)(p + 4);
                    ushort4 o0, o1;
                    o0.x = f2bs(w0.x); o0.y = f2bs(w0.y); o0.z = f2bs(w0.z); o0.w = f2bs(w0.w);
                    o1.x = f2bs(w1.x); o1.y = f2bs(w1.y); o1.z = f2bs(w1.z); o1.w = f2bs(w1.w);
                    *(ushort4*)&Ws[buf][row][sblk]     = o0;
                    *(ushort4*)&Ws[buf][row][sblk + 4] = o1;
                }
            }
        }
    };

    stage(0, 0);
    asm volatile("s_waitcnt vmcnt(0)" ::: "memory");
    __syncthreads();

    int cur = 0;
    for (int kt = 0; kt < 4; ++kt) {
        if (kt + 1 < 4) stage(cur ^ 1, (kt + 1) << 6);
        bf16x8 af[2][2], bfr[2][2];
        #pragma unroll
        for (int i = 0; i < 2; ++i) {
            #pragma unroll
            for (int ks = 0; ks < 2; ++ks) {
                int ca = ((ks * 4 + lq) ^ (lr & 7)) * 8;
                af[i][ks]  = *(const bf16x8*)&As[cur][wr * 32 + i * 16 + lr][ca];
                bfr[i][ks] = *(const bf16x8*)&Ws[cur][wc * 32 + i * 16 + lr][ca];
            }
        }
        #pragma unroll
        for (int ks = 0; ks < 2; ++ks)
            #pragma unroll
            for (int i = 0; i < 2; ++i)
                #pragma unroll
                for (int j = 0; j < 2; ++j)
                    acc[i][j] = __builtin_amdgcn_mfma_f32_16x16x32_bf16(af[i][ks], bfr[j][ks], acc[i][j], 0, 0, 0);
        if (kt + 1 < 4) {
            asm volatile("s_waitcnt vmcnt(0)" ::: "memory");
            __syncthreads();
            cur ^= 1;
        }
    }

    // write xdbl (cols < 48) and dt slice (cols < 16) hi/lo to LDS
    #pragma unroll
    for (int i = 0; i < 2; ++i) {
        #pragma unroll
        for (int j = 0; j < 2; ++j) {
            const int col = wc * 32 + j * 16 + lr;
            #pragma unroll
            for (int e = 0; e < 4; ++e) {
                const int row = wr * 32 + i * 16 + lq * 4 + e;
                float t = acc[i][j][e];
                if (col < 48) xdbl[(size_t)(bm + row) * 48 + col] = t;
                if (wc == 0 && j == 0) {   // cols 0..15
                    unsigned short hi = f2bs(t);
                    Ahl[row][lr]      = hi;
                    Ahl[row][16 + lr] = f2bs(t - bf2f(hi));
                }
            }
        }
    }
    __syncthreads();

    // Phase 2: delta[64 rows][256 cols]; wave wid handles cols wid*64..+63
    const int wcol = wid * 64;
    const int kc = (lq & 1) * 8;           // duplicated-W col base
    bf16x8 bf[4];
    #pragma unroll
    for (int j = 0; j < 4; ++j) {
        int nrow = wcol + j * 16 + lr;
        if (wbf) {
            bf[j] = *(const bf16x8*)((const unsigned short*)Wd + (size_t)nrow * 16 + kc);
        } else {
            const float* p = (const float*)Wd + (size_t)nrow * 16 + kc;
            float4 w0 = *(const float4*)p;
            float4 w1 = *(const float4*)(p + 4);
            union { bf16x8 v; unsigned short s[8]; } u8;
            u8.s[0] = f2bs(w0.x); u8.s[1] = f2bs(w0.y); u8.s[2] = f2bs(w0.z); u8.s[3] = f2bs(w0.w);
            u8.s[4] = f2bs(w1.x); u8.s[5] = f2bs(w1.y); u8.s[6] = f2bs(w1.z); u8.s[7] = f2bs(w1.w);
            bf[j] = u8.v;
        }
    }
    bf16x8 af2[4];
    #pragma unroll
    for (int i = 0; i < 4; ++i)
        af2[i] = *(const bf16x8*)&Ahl[i * 16 + lr][lq * 8];

    f32x4 acc2[4][4] = {};
    #pragma unroll
    for (int i = 0; i < 4; ++i)
        #pragma unroll
        for (int j = 0; j < 4; ++j)
            acc2[i][j] = __builtin_amdgcn_mfma_f32_16x16x32_bf16(af2[i], bf[j], acc2[i][j], 0, 0, 0);

    #pragma unroll
    for (int i = 0; i < 4; ++i) {
        #pragma unroll
        for (int j = 0; j < 4; ++j) {
            const int col = wcol + j * 16 + lr;
            #pragma unroll
            for (int e = 0; e < 4; ++e) {
                const int row = i * 16 + lq * 4 + e;
                float t = acc2[i][j][e] + ldw(bias, col, wbf);
                t = (t > 20.f) ? t : log1pf(__expf(t));
                delta[(size_t)(bm + row) * 256 + col] = f2bs(t);
            }
        }
    }
}

// ------------------------------------------------- depthwise conv3 + SiLU (8 rows/block, 8 ch/thread, reg weights)
__global__ __launch_bounds__(256) void conv_silu_kernel(
    const unsigned short* __restrict__ xz,
    const void* __restrict__ wx, const void* __restrict__ wz,
    unsigned short* __restrict__ u, unsigned short* __restrict__ z,
    const int* __restrict__ flagp)
{
    const bool wbf = (*flagp != 0);
    int sub = threadIdx.x >> 5;
    int cb = (threadIdx.x & 31) * 8;
    int bl = blockIdx.x * 8 + sub;
    int l = bl % L_;
    const unsigned short* r = xz + (size_t)bl * 512;
    bool hasm = (l > 0), hasp = (l < L_ - 1);

    float wxa[24], wza[24];
    if (wbf) {
        const unsigned short* px = (const unsigned short*)wx + 3 * cb;
        const unsigned short* pz = (const unsigned short*)wz + 3 * cb;
        #pragma unroll
        for (int t = 0; t < 3; ++t) {
            cvt4(*(const ushort4*)(px + t * 8), &wxa[t * 8]);
            cvt4(*(const ushort4*)(px + t * 8 + 4), &wxa[t * 8 + 4]);
            cvt4(*(const ushort4*)(pz + t * 8), &wza[t * 8]);
            cvt4(*(const ushort4*)(pz + t * 8 + 4), &wza[t * 8 + 4]);
        }
    } else {
        const float* px = (const float*)wx + 3 * cb;
        const float* pz = (const float*)wz + 3 * cb;
        #pragma unroll
        for (int t = 0; t < 6; ++t) {
            *(float4*)&wxa[t * 4] = *(const float4*)(px + t * 4);
            *(float4*)&wza[t * 4] = *(const float4*)(pz + t * 4);
        }
    }

    float xm[8], xc[8], xp[8];
    cvt8g(r + cb - 512, hasm, xm);
    cvt8g(r + cb,       true, xc);
    cvt8g(r + cb + 512, hasp, xp);
    ushort4 o0, o1;
    {
        unsigned short* op = (unsigned short*)&o0;
        unsigned short* op1 = (unsigned short*)&o1;
        #pragma unroll
        for (int j = 0; j < 8; ++j) {
            float v = xm[j] * wxa[3 * j] + xc[j] * wxa[3 * j + 1] + xp[j] * wxa[3 * j + 2];
            v = v / (1.f + __expf(-v));
            if (j < 4) op[j] = f2bs(v); else op1[j - 4] = f2bs(v);
        }
    }
    *(ushort4*)(u + (size_t)bl * 256 + cb) = o0;
    *(ushort4*)(u + (size_t)bl * 256 + cb + 4) = o1;

    cvt8g(r + cb - 256,  hasm, xm);
    cvt8g(r + 256 + cb,  true, xc);
    cvt8g(r + 768 + cb,  hasp, xp);
    {
        unsigned short* op = (unsigned short*)&o0;
        unsigned short* op1 = (unsigned short*)&o1;
        #pragma unroll
        for (int j = 0; j < 8; ++j) {
            float v = xm[j] * wza[3 * j] + xc[j] * wza[3 * j + 1] + xp[j] * wza[3 * j + 2];
            v = v / (1.f + __expf(-v));
            if (j < 4) op[j] = f2bs(v); else op1[j - 4] = f2bs(v);
        }
    }
    *(ushort4*)(z + (size_t)bl * 256 + cb) = o0;
    *(ushort4*)(z + (size_t)bl * 256 + cb + 4) = o1;
}

// ------------------------------------------------- selective scan (transposed LDS, b128-batched)
__global__ __launch_bounds__(256) void scan_a_kernel(
    const unsigned short* __restrict__ delta, const unsigned short* __restrict__ u,
    const float* __restrict__ xdbl, const void* __restrict__ A_log,
    float* __restrict__ hend, float* __restrict__ dsum, const int* __restrict__ flagp)
{
    const bool wbf = (*flagp != 0);
    int blk = blockIdx.x;
    int b = blk / (NCH * 16);
    int rem = blk % (NCH * 16);
    int c = rem / 16, db = rem % 16;

    __shared__ unsigned int sduT[16][68];   // [d-group][t2], packed delta|u
    __shared__ float sBT[16][68];           // [n][t2]

    const unsigned short* dp = delta + (size_t)b * L_ * 256;
    const unsigned short* up = u     + (size_t)b * L_ * 256;
    const float* xd = xdbl + (size_t)b * L_ * 48;

    int r = threadIdx.x >> 2, q = (threadIdx.x & 3) * 4;
    int lrow = c * 64 + r;
    {
        ushort4 dv = *(const ushort4*)(dp + (size_t)lrow * 256 + db * 16 + q);
        ushort4 uv = *(const ushort4*)(up + (size_t)lrow * 256 + db * 16 + q);
        sduT[q + 0][r] = (unsigned)dv.x | ((unsigned)uv.x << 16);
        sduT[q + 1][r] = (unsigned)dv.y | ((unsigned)uv.y << 16);
        sduT[q + 2][r] = (unsigned)dv.z | ((unsigned)uv.z << 16);
        sduT[q + 3][r] = (unsigned)dv.w | ((unsigned)uv.w << 16);
        float4 Bv = *(const float4*)(xd + (size_t)lrow * 48 + 16 + q);
        sBT[q + 0][r] = Bv.x; sBT[q + 1][r] = Bv.y;
        sBT[q + 2][r] = Bv.z; sBT[q + 3][r] = Bv.w;
    }
    __syncthreads();

    int g = threadIdx.x >> 4, n = threadIdx.x & 15;
    int d = db * 16 + g;
    float An2 = -__expf(ldw(A_log, d * 16 + n, wbf)) * 1.44269504088896f;
    float h = 0.f, s = 0.f;
    #pragma unroll 4
    for (int tb = 0; tb < 16; ++tb) {
        uint4 du4 = *(const uint4*)&sduT[g][tb * 4];
        float4 B4 = *(const float4*)&sBT[n][tb * 4];
        #pragma unroll
        for (int j = 0; j < 4; ++j) {
            unsigned du = (j == 0) ? du4.x : (j == 1) ? du4.y : (j == 2) ? du4.z : du4.w;
            float Bn = (j == 0) ? B4.x : (j == 1) ? B4.y : (j == 2) ? B4.z : B4.w;
            float ds = __uint_as_float(du << 16);
            float ut = __uint_as_float(du & 0xFFFF0000u);
            float e = exp2f(ds * An2);
            h = fmaf(e, h, ds * ut * Bn);
            s += ds;
        }
    }
    size_t pair = (size_t)b * 256 + d;
    hend[(pair * NCH + c) * 16 + n] = h;
    if (n == 0) dsum[pair * NCH + c] = s;
}

// ------------------------------------------------- combine (256 blocks x 64 thr, 7x7 prefetch)
__global__ __launch_bounds__(64) void scan_b_kernel(
    const void* __restrict__ A_log, float* __restrict__ hend,
    const float* __restrict__ dsum, const int* __restrict__ flagp)
{
    const bool wbf = (*flagp != 0);
    int gid = blockIdx.x * 64 + threadIdx.x;   // 16384
    int pair = gid >> 4, n = gid & 15;
    int d = pair & 255;
    float An = -__expf(ldw(A_log, d * 16 + n, wbf));
    float H = 0.f;
    #pragma unroll 1
    for (int c0 = 0; c0 < NCH; c0 += 7) {
        float he[7], dd[7];
        #pragma unroll
        for (int j = 0; j < 7; ++j) {
            he[j] = hend[((size_t)pair * NCH + c0 + j) * 16 + n];
            dd[j] = dsum[(size_t)pair * NCH + c0 + j];
        }
        #pragma unroll
        for (int j = 0; j < 7; ++j) {
            hend[((size_t)pair * NCH + c0 + j) * 16 + n] = H;
            H = __expf(An * dd[j]) * H + he[j];
        }
    }
}

__global__ __launch_bounds__(256) void scan_c_kernel(
    const unsigned short* __restrict__ delta, const unsigned short* __restrict__ u,
    const float* __restrict__ xdbl, const void* __restrict__ A_log,
    const void* __restrict__ Dp, const float* __restrict__ hinit,
    unsigned short* __restrict__ y, const int* __restrict__ flagp)
{
    const bool wbf = (*flagp != 0);
    int blk = blockIdx.x;
    int b = blk / (NCH * 16);
    int rem = blk % (NCH * 16);
    int c = rem / 16, db = rem % 16;

    __shared__ unsigned int sduT[16][68];    // [d-group][t2]
    __shared__ float sBCT[16][132];          // [n][t2*2 + {B,C}]
    __shared__ float sypT[16][4][68];        // [d-group][quad][t2]
    __shared__ unsigned short sy[64][16];

    const unsigned short* dp = delta + (size_t)b * L_ * 256;
    const unsigned short* up = u     + (size_t)b * L_ * 256;
    const float* xd = xdbl + (size_t)b * L_ * 48;

    int r = threadIdx.x >> 2, q = (threadIdx.x & 3) * 4;
    int lrow = c * 64 + r;
    {
        ushort4 dv = *(const ushort4*)(dp + (size_t)lrow * 256 + db * 16 + q);
        ushort4 uv = *(const ushort4*)(up + (size_t)lrow * 256 + db * 16 + q);
        sduT[q + 0][r] = (unsigned)dv.x | ((unsigned)uv.x << 16);
        sduT[q + 1][r] = (unsigned)dv.y | ((unsigned)uv.y << 16);
        sduT[q + 2][r] = (unsigned)dv.z | ((unsigned)uv.z << 16);
        sduT[q + 3][r] = (unsigned)dv.w | ((unsigned)uv.w << 16);
        float4 Bv = *(const float4*)(xd + (size_t)lrow * 48 + 16 + q);
        float4 Cv = *(const float4*)(xd + (size_t)lrow * 48 + 32 + q);
        float2 t0; t0.x = Bv.x; t0.y = Cv.x; *(float2*)&sBCT[q + 0][r * 2] = t0;
        float2 t1; t1.x = Bv.y; t1.y = Cv.y; *(float2*)&sBCT[q + 1][r * 2] = t1;
        float2 t2; t2.x = Bv.z; t2.y = Cv.z; *(float2*)&sBCT[q + 2][r * 2] = t2;
        float2 t3; t3.x = Bv.w; t3.y = Cv.w; *(float2*)&sBCT[q + 3][r * 2] = t3;
    }
    __syncthreads();

    int g = threadIdx.x >> 4, n = threadIdx.x & 15;
    int d = db * 16 + g;
    float An2 = -__expf(ldw(A_log, d * 16 + n, wbf)) * 1.44269504088896f;
    size_t pair = (size_t)b * 256 + d;
    float h = hinit[(pair * NCH + c) * 16 + n];
    const bool wlane = ((n & 3) == 0);
    const int p = n >> 2;
    #pragma unroll 4
    for (int tb = 0; tb < 16; ++tb) {
        uint4 du4 = *(const uint4*)&sduT[g][tb * 4];
        float4 bc01 = *(const float4*)&sBCT[n][tb * 8];
        float4 bc23 = *(const float4*)&sBCT[n][tb * 8 + 4];
        float yp4[4];
        #pragma unroll
        for (int j = 0; j < 4; ++j) {
            unsigned du = (j == 0) ? du4.x : (j == 1) ? du4.y : (j == 2) ? du4.z : du4.w;
            float Bn = (j == 0) ? bc01.x : (j == 1) ? bc01.z : (j == 2) ? bc23.x : bc23.z;
            float Cn = (j == 0) ? bc01.y : (j == 1) ? bc01.w : (j == 2) ? bc23.y : bc23.w;
            float ds = __uint_as_float(du << 16);
            float ut = __uint_as_float(du & 0xFFFF0000u);
            float e = exp2f(ds * An2);
            h = fmaf(e, h, ds * ut * Bn);
            float yp = h * Cn;
            yp = dpp_add_xor1(yp);
            yp = dpp_add_xor2(yp);
            yp4[j] = yp;
        }
        if (wlane) *(float4*)&sypT[g][p][tb * 4] = *(float4*)yp4;
    }
    __syncthreads();

    #pragma unroll
    for (int cc = 0; cc < 4; ++cc) {
        int cell = threadIdx.x + cc * 256;
        int t2 = cell >> 4, gg = cell & 15;
        float sum = sypT[gg][0][t2] + sypT[gg][1][t2] + sypT[gg][2][t2] + sypT[gg][3][t2];
        unsigned du = sduT[gg][t2];
        float ut = __uint_as_float(du & 0xFFFF0000u);
        float Dd = ldw(Dp, db * 16 + gg, wbf);
        sy[t2][gg] = f2bs(sum + ut * Dd);
    }
    __syncthreads();
    *(ushort4*)(y + ((size_t)b * L_ + c * 64 + r) * 256 + db * 16 + q) = *(ushort4*)&sy[r][q];
}

// ------------------------------------------------- launch
extern "C" void kernel_launch(void* const* d_in, const int* in_sizes, int n_in,
                              void* d_out, int out_size, void* d_ws, size_t ws_size,
                              hipStream_t stream) {
    const void* x         = d_in[0];
    const void* ln1_g     = d_in[1];
    const void* ln1_b     = d_in[2];
    const void* ln2_g     = d_in[3];
    const void* ln2_b     = d_in[4];
    const void* in_proj_w = d_in[5];
    const void* conv_x_w  = d_in[6];
    const void* conv_z_w  = d_in[7];
    const void* x_proj_w  = d_in[8];
    const void* dt_proj_w = d_in[9];
    const void* dt_proj_b = d_in[10];
    const void* A_log     = d_in[11];
    const void* Dp        = d_in[12];
    const void* out_proj_w= d_in[13];
    const void* mlp_w1    = d_in[14];
    const void* mlp_b1    = d_in[15];
    const void* mlp_w2    = d_in[16];
    const void* mlp_b2    = d_in[17];

    float* ws = (float*)d_ws;
    unsigned short* xz    = (unsigned short*)(ws);
    unsigned short* delta = (unsigned short*)(ws);
    unsigned short* yb    = (unsigned short*)(ws + 1605632);
    float*          xdbl  = ws + 3211264;
    float*          hend  = ws + 3813376;
    float*          dsum  = ws + 4616192;
    unsigned short* hmid  = (unsigned short*)(ws);
    unsigned short* ub    = (unsigned short*)(ws + 6422528);
    unsigned short* xres  = (unsigned short*)(ws + 6422528);
    unsigned short* xnb   = (unsigned short*)(ws + 8028160);  // xn / z / xn2
    int*            flag  = (int*)(ws + 9633792);

    dim3 blk(256);
    const int KNOSPLIT = 1 << 30;

    // 0. dtype detection -> flag
    detect_kernel<<<1, blk, 0, stream>>>((const unsigned int*)x, flag);

    // 1. LN1: x(dual) -> xn (bf16)
    ln_kernel<<<M_ / 4, blk, 0, stream>>>(x, -1, ln1_g, ln1_b, xnb, flag);

    // 2. in_proj (MFMA, 64x128 tile): xn x W(512,256)^T -> xz (M,512) bf16
    mgemm_kernel<EPI_NONE, 2><<<dim3(4, 196), blk, 0, stream>>>(
        xnb, nullptr, KNOSPLIT, in_proj_w, xz, 512, 256, 256, 512, nullptr, nullptr, nullptr, flag);

    // 3. conv+silu: xz -> u (bf16), z (bf16 -> xnb, xn dead)
    conv_silu_kernel<<<M_ / 8, blk, 0, stream>>>(xz, conv_x_w, conv_z_w, ub, xnb, flag);

    // 4. x_proj + dt_proj + softplus (fused MFMA): u -> xdbl (fp32), delta (bf16)
    xdt_kernel<<<dim3(1, 196), blk, 0, stream>>>(
        ub, x_proj_w, dt_proj_w, xdbl, delta, dt_proj_b, flag);

    // 5-7. selective scan
    scan_a_kernel<<<B_ * NCH * 16, blk, 0, stream>>>(delta, ub, xdbl, A_log, hend, dsum, flag);
    scan_b_kernel<<<256, dim3(64), 0, stream>>>(A_log, hend, dsum, flag);
    scan_c_kernel<<<B_ * NCH * 16, blk, 0, stream>>>(delta, ub, xdbl, A_log, Dp, hend, yb, flag);

    // 8. out_proj + residual (MFMA, split A = [y | z]) -> xres bf16
    mgemm_kernel<EPI_RES, 1><<<dim3(4, 196), blk, 0, stream>>>(
        yb, xnb, 256, out_proj_w, xres, 256, 512, 256, 256, nullptr, x, nullptr, flag);

    // 9. LN2: xres -> xn2 (bf16 -> xnb, z dead)
    ln_kernel<<<M_ / 4, blk, 0, stream>>>(xres, 1, ln2_g, ln2_b, xnb, flag);

    // 10. MLP1 + bias + GELU (MFMA, 64x128 tile): xn2 x W(1024,256)^T -> hmid bf16
    mgemm_kernel<EPI_GELU, 2><<<dim3(8, 196), blk, 0, stream>>>(
        xnb, nullptr, KNOSPLIT, mlp_w1, hmid, 1024, 256, 256, 1024, mlp_b1, nullptr, nullptr, flag);

    // 11. MLP2 + bias + residual (MFMA) -> d_out (dtype per flag)
    mgemm_kernel<EPI_OUT, 1><<<dim3(4, 196), blk, 0, stream>>>(
        hmid, nullptr, KNOSPLIT, mlp_w2, d_out, 256, 1024, 1024, 256, mlp_b2, nullptr, xres, flag);
}

// Round 11
// 295.380 us; speedup vs baseline: 1.4610x; 1.4610x over previous
//
#include <hip/hip_runtime.h>
#include <hip/hip_bf16.h>

#define B_ 4
#define L_ 3136
#define D_ 256
#define NCH 49     // 49 chunks * 64 = 3136
#define LCH 64
#define M_ (B_*L_)

__device__ __forceinline__ float bf2f(unsigned short u) {
    union { unsigned int i; float f; } v; v.i = ((unsigned int)u) << 16; return v.f;
}
__device__ __forceinline__ unsigned short f2bs(float f) {
    __hip_bfloat16 h = __float2bfloat16(f);
    return *(unsigned short*)&h;
}
// dual-dtype load for INPUT tensors (bf16 if flag, else fp32)
__device__ __forceinline__ float ldw(const void* p, size_t i, bool bf) {
    return bf ? bf2f(((const unsigned short*)p)[i]) : ((const float*)p)[i];
}
__device__ __forceinline__ void cvt4(ushort4 a, float* o) {
    o[0] = bf2f(a.x); o[1] = bf2f(a.y); o[2] = bf2f(a.z); o[3] = bf2f(a.w);
}
__device__ __forceinline__ void cvt8g(const unsigned short* p, bool v, float* o) {
    if (v) {
        ushort4 a = *(const ushort4*)p;
        ushort4 b = *(const ushort4*)(p + 4);
        cvt4(a, o); cvt4(b, o + 4);
    } else {
        #pragma unroll
        for (int i = 0; i < 8; ++i) o[i] = 0.f;
    }
}
// DPP cross-lane adds within quads (xor1 / xor2) -- pure VALU, no LDS pipe
__device__ __forceinline__ float dpp_add_xor1(float x) {
    int m = __builtin_amdgcn_update_dpp(0, __float_as_int(x), 0xB1, 0xF, 0xF, true);
    return x + __int_as_float(m);
}
__device__ __forceinline__ float dpp_add_xor2(float x) {
    int m = __builtin_amdgcn_update_dpp(0, __float_as_int(x), 0x4E, 0xF, 0xF, true);
    return x + __int_as_float(m);
}

// ------------------------------------------------- dtype detection
__global__ __launch_bounds__(256) void detect_kernel(
    const unsigned int* __restrict__ xw, int* __restrict__ flag)
{
    int t = threadIdx.x; int cnt = 0;
    for (int i = t; i < 2048; i += 256) {
        unsigned int lo = xw[i] & 0xFFFFu;
        unsigned int e = (lo >> 7) & 0xFFu;
        if (e >= 0x58u && e <= 0x97u) cnt++;
    }
    #pragma unroll
    for (int o = 32; o > 0; o >>= 1) cnt += __shfl_down(cnt, o);
    __shared__ int sred[4];
    if ((t & 63) == 0) sred[t >> 6] = cnt;
    __syncthreads();
    if (t == 0) flag[0] = (sred[0] + sred[1] + sred[2] + sred[3] > 1024) ? 1 : 0;
}

// ------------------------------------------------- LayerNorm (1 wave = 1 row, 4 elem/thread)
__global__ __launch_bounds__(256) void ln_kernel(
    const void* __restrict__ xin, int inmode,   // -1: dual via flag; 1: bf16
    const void* __restrict__ g, const void* __restrict__ bsh,
    unsigned short* __restrict__ out, const int* __restrict__ flagp)
{
    const bool wbf = (*flagp != 0);
    const bool inbf = (inmode < 0) ? wbf : true;
    int row = blockIdx.x * 4 + (threadIdx.x >> 6);
    int lane = threadIdx.x & 63;
    size_t idx = (size_t)row * 256 + lane * 4;
    float v[4];
    if (inbf) {
        ushort4 a = *(const ushort4*)((const unsigned short*)xin + idx);
        cvt4(a, v);
    } else {
        float4 a = *(const float4*)((const float*)xin + idx);
        v[0] = a.x; v[1] = a.y; v[2] = a.z; v[3] = a.w;
    }
    float s = v[0] + v[1] + v[2] + v[3];
    float s2 = v[0]*v[0] + v[1]*v[1] + v[2]*v[2] + v[3]*v[3];
    #pragma unroll
    for (int o = 32; o > 0; o >>= 1) { s += __shfl_xor(s, o); s2 += __shfl_xor(s2, o); }
    float mean = s * (1.f / 256.f);
    float var  = s2 * (1.f / 256.f) - mean * mean;
    float rs = rsqrtf(var + 1e-5f);
    ushort4 o;
    o.x = f2bs((v[0] - mean) * rs * ldw(g, lane*4+0, wbf) + ldw(bsh, lane*4+0, wbf));
    o.y = f2bs((v[1] - mean) * rs * ldw(g, lane*4+1, wbf) + ldw(bsh, lane*4+1, wbf));
    o.z = f2bs((v[2] - mean) * rs * ldw(g, lane*4+2, wbf) + ldw(bsh, lane*4+2, wbf));
    o.w = f2bs((v[3] - mean) * rs * ldw(g, lane*4+3, wbf) + ldw(bsh, lane*4+3, wbf));
    *(ushort4*)(out + idx) = o;
}

// ------------------------------------------------- epilogue tags
enum { EPI_NONE = 0, EPI_SP = 1, EPI_RES = 2, EPI_GELU = 3, EPI_OUT = 4 };

typedef __attribute__((ext_vector_type(8))) short bf16x8;
typedef __attribute__((ext_vector_type(4))) float f32x4;

__device__ __forceinline__ void gload_lds16(const void* g, void* l) {
    __builtin_amdgcn_global_load_lds(
        (const __attribute__((address_space(1))) unsigned int*)g,
        (__attribute__((address_space(3))) unsigned int*)l, 16, 0, 0);
}

// ------------------------------------------------- MFMA bf16 GEMM (64x64x64, dbuf, XOR-swizzle)
template<int EPI>
__global__ __launch_bounds__(256) void mgemm_kernel(
    const unsigned short* __restrict__ A, const unsigned short* __restrict__ A2, int Ksplit,
    const void* __restrict__ W, void* __restrict__ Cout,
    int N, int K, int lda, int ldc,
    const void* __restrict__ bias, const void* __restrict__ resb,
    const unsigned short* __restrict__ resf, const int* __restrict__ flagp)
{
    const bool wbf = (*flagp != 0);
    __shared__ unsigned short As[2][64][64];
    __shared__ unsigned short Ws[2][64][64];
    const int tid = threadIdx.x;

    const int nwg = gridDim.x * gridDim.y;
    int bid = blockIdx.y * gridDim.x + blockIdx.x;
    int wgid = ((nwg & 7) == 0) ? ((bid & 7) * (nwg >> 3) + (bid >> 3)) : bid;
    const int bx = wgid % gridDim.x;
    const int by = wgid / gridDim.x;
    const int bm = by * 64, bn = bx * 64;

    const int l = tid & 63, wid = tid >> 6;
    const int wr = wid >> 1, wc = wid & 1;
    const int lr = l & 15;
    const int lq = l >> 4;
    const int srow = tid >> 3;
    const int sblk = ((tid & 7) ^ (srow & 7)) * 8;
    const int dcol = (tid & 7) * 8;

    f32x4 acc[2][2] = {};
    const int NT = K >> 6;

    auto stage = [&](int buf, int k0s) {
        const unsigned short* Ab; int kc;
        if (k0s < Ksplit) { Ab = A;  kc = k0s; }
        else              { Ab = A2; kc = k0s - Ksplit; }
        gload_lds16(Ab + (size_t)(bm + srow) * lda + kc + sblk,      &As[buf][srow][dcol]);
        gload_lds16(Ab + (size_t)(bm + 32 + srow) * lda + kc + sblk, &As[buf][32 + srow][dcol]);
        if (wbf) {
            const unsigned short* Wb = (const unsigned short*)W;
            gload_lds16(Wb + (size_t)(bn + srow) * K + k0s + sblk,      &Ws[buf][srow][dcol]);
            gload_lds16(Wb + (size_t)(bn + 32 + srow) * K + k0s + sblk, &Ws[buf][32 + srow][dcol]);
        } else {
            const float* Wf = (const float*)W;
            #pragma unroll
            for (int h = 0; h < 2; ++h) {
                int row = h * 32 + srow;
                const float* p = Wf + (size_t)(bn + row) * K + k0s + (tid & 7) * 8;
                float4 w0 = *(const float4*)p;
                float4 w1 = *(const float4*)(p + 4);
                ushort4 o0, o1;
                o0.x = f2bs(w0.x); o0.y = f2bs(w0.y); o0.z = f2bs(w0.z); o0.w = f2bs(w0.w);
                o1.x = f2bs(w1.x); o1.y = f2bs(w1.y); o1.z = f2bs(w1.z); o1.w = f2bs(w1.w);
                *(ushort4*)&Ws[buf][row][sblk]     = o0;
                *(ushort4*)&Ws[buf][row][sblk + 4] = o1;
            }
        }
    };

    stage(0, 0);
    asm volatile("s_waitcnt vmcnt(0)" ::: "memory");
    __syncthreads();

    int cur = 0;
    for (int kt = 0; kt < NT; ++kt) {
        if (kt + 1 < NT) stage(cur ^ 1, (kt + 1) << 6);

        bf16x8 af[2][2], bfr[2][2];
        #pragma unroll
        for (int i = 0; i < 2; ++i) {
            #pragma unroll
            for (int ks = 0; ks < 2; ++ks) {
                int ca = ((ks * 4 + lq) ^ (lr & 7)) * 8;
                af[i][ks]  = *(const bf16x8*)&As[cur][wr * 32 + i * 16 + lr][ca];
                bfr[i][ks] = *(const bf16x8*)&Ws[cur][wc * 32 + i * 16 + lr][ca];
            }
        }
        #pragma unroll
        for (int ks = 0; ks < 2; ++ks)
            #pragma unroll
            for (int i = 0; i < 2; ++i)
                #pragma unroll
                for (int j = 0; j < 2; ++j)
                    acc[i][j] = __builtin_amdgcn_mfma_f32_16x16x32_bf16(af[i][ks], bfr[j][ks], acc[i][j], 0, 0, 0);

        if (kt + 1 < NT) {
            asm volatile("s_waitcnt vmcnt(0)" ::: "memory");
            __syncthreads();
            cur ^= 1;
        }
    }

    #pragma unroll
    for (int i = 0; i < 2; ++i) {
        #pragma unroll
        for (int j = 0; j < 2; ++j) {
            const int col = bn + wc * 32 + j * 16 + lr;
            #pragma unroll
            for (int e = 0; e < 4; ++e) {
                const int row = bm + wr * 32 + i * 16 + lq * 4 + e;
                float t = acc[i][j][e];
                if (EPI == EPI_RES) {
                    t += ldw(resb, (size_t)row * 256 + col, wbf);
                } else if (EPI == EPI_GELU) {
                    t += ldw(bias, col, wbf);
                    t = 0.5f * t * (1.f + erff(t * 0.70710678118654752f));
                } else if (EPI == EPI_OUT) {
                    t += ldw(bias, col, wbf) + bf2f(resf[(size_t)row * 256 + col]);
                }
                if (EPI == EPI_OUT && !wbf) {
                    ((float*)Cout)[(size_t)row * ldc + col] = t;
                } else {
                    ((unsigned short*)Cout)[(size_t)row * ldc + col] = f2bs(t);
                }
            }
        }
    }
}

// ------------------------------------------------- x_proj MFMA: u(M,256)bf16 x W(48,256)^T -> xdbl(M,48) fp32
__global__ __launch_bounds__(256) void xproj_kernel(
    const unsigned short* __restrict__ A, const void* __restrict__ W,
    float* __restrict__ Cout, const int* __restrict__ flagp)
{
    const bool wbf = (*flagp != 0);
    __shared__ unsigned short As[2][64][64];
    __shared__ unsigned short Ws[2][64][64];
    const int tid = threadIdx.x;
    const int bm = blockIdx.y * 64;   // gridDim.x == 1

    const int l = tid & 63, wid = tid >> 6;
    const int wr = wid >> 1, wc = wid & 1;
    const int lr = l & 15, lq = l >> 4;
    const int srow = tid >> 3;
    const int sblk = ((tid & 7) ^ (srow & 7)) * 8;
    const int dcol = (tid & 7) * 8;

    // zero W rows 48..63 of both buffers (stay zero across all K-tiles)
    {
        ushort4 zz4; zz4.x = 0; zz4.y = 0; zz4.z = 0; zz4.w = 0;
        int buf = tid >> 7, rr = 48 + ((tid >> 3) & 15), cc = (tid & 7) * 8;
        *(ushort4*)&Ws[buf][rr][cc] = zz4;
        *(ushort4*)&Ws[buf][rr][cc + 4] = zz4;
    }
    __syncthreads();

    f32x4 acc[2][2] = {};

    auto stage = [&](int buf, int k0s) {
        gload_lds16(A + (size_t)(bm + srow) * 256 + k0s + sblk,      &As[buf][srow][dcol]);
        gload_lds16(A + (size_t)(bm + 32 + srow) * 256 + k0s + sblk, &As[buf][32 + srow][dcol]);
        if (wbf) {
            const unsigned short* Wb = (const unsigned short*)W;
            gload_lds16(Wb + (size_t)srow * 256 + k0s + sblk, &Ws[buf][srow][dcol]);
            if (srow < 16)
                gload_lds16(Wb + (size_t)(32 + srow) * 256 + k0s + sblk, &Ws[buf][32 + srow][dcol]);
        } else {
            const float* Wf = (const float*)W;
            #pragma unroll
            for (int h = 0; h < 2; ++h) {
                int row = h * 32 + srow;
                if (row < 48) {
                    const float* p = Wf + (size_t)row * 256 + k0s + (tid & 7) * 8;
                    float4 w0 = *(const float4*)p;
                    float4 w1 = *(const float4*)(p + 4);
                    ushort4 o0, o1;
                    o0.x = f2bs(w0.x); o0.y = f2bs(w0.y); o0.z = f2bs(w0.z); o0.w = f2bs(w0.w);
                    o1.x = f2bs(w1.x); o1.y = f2bs(w1.y); o1.z = f2bs(w1.z); o1.w = f2bs(w1.w);
                    *(ushort4*)&Ws[buf][row][sblk]     = o0;
                    *(ushort4*)&Ws[buf][row][sblk + 4] = o1;
                }
            }
        }
    };

    stage(0, 0);
    asm volatile("s_waitcnt vmcnt(0)" ::: "memory");
    __syncthreads();

    int cur = 0;
    for (int kt = 0; kt < 4; ++kt) {
        if (kt + 1 < 4) stage(cur ^ 1, (kt + 1) << 6);
        bf16x8 af[2][2], bfr[2][2];
        #pragma unroll
        for (int i = 0; i < 2; ++i) {
            #pragma unroll
            for (int ks = 0; ks < 2; ++ks) {
                int ca = ((ks * 4 + lq) ^ (lr & 7)) * 8;
                af[i][ks]  = *(const bf16x8*)&As[cur][wr * 32 + i * 16 + lr][ca];
                bfr[i][ks] = *(const bf16x8*)&Ws[cur][wc * 32 + i * 16 + lr][ca];
            }
        }
        #pragma unroll
        for (int ks = 0; ks < 2; ++ks)
            #pragma unroll
            for (int i = 0; i < 2; ++i)
                #pragma unroll
                for (int j = 0; j < 2; ++j)
                    acc[i][j] = __builtin_amdgcn_mfma_f32_16x16x32_bf16(af[i][ks], bfr[j][ks], acc[i][j], 0, 0, 0);
        if (kt + 1 < 4) {
            asm volatile("s_waitcnt vmcnt(0)" ::: "memory");
            __syncthreads();
            cur ^= 1;
        }
    }

    #pragma unroll
    for (int i = 0; i < 2; ++i) {
        #pragma unroll
        for (int j = 0; j < 2; ++j) {
            const int col = wc * 32 + j * 16 + lr;
            if (col < 48) {
                #pragma unroll
                for (int e = 0; e < 4; ++e) {
                    const int row = bm + wr * 32 + i * 16 + lq * 4 + e;
                    Cout[(size_t)row * 48 + col] = acc[i][j][e];
                }
            }
        }
    }
}

// ------------------------------------------------- dt_proj MFMA (hi/lo split, K=16) + softplus
__global__ __launch_bounds__(256) void dtgemm_kernel(
    const float* __restrict__ Axd, const void* __restrict__ W,
    unsigned short* __restrict__ Cout, const void* __restrict__ bias,
    const int* __restrict__ flagp)
{
    const bool wbf = (*flagp != 0);
    __shared__ unsigned short Ah[64][16];
    __shared__ unsigned short Al[64][16];
    __shared__ unsigned short Wb[64][16];
    const int tid = threadIdx.x;
    const int nwg = gridDim.x * gridDim.y;
    int bid = blockIdx.y * gridDim.x + blockIdx.x;
    int wgid = ((nwg & 7) == 0) ? ((bid & 7) * (nwg >> 3) + (bid >> 3)) : bid;
    const int bx = wgid % gridDim.x, by = wgid / gridDim.x;
    const int bm = by * 64, bn = bx * 64;

    {
        int rr = tid >> 2, cc = (tid & 3) * 4;
        float4 v = *(const float4*)(Axd + (size_t)(bm + rr) * 48 + cc);
        float vv[4] = {v.x, v.y, v.z, v.w};
        ushort4 hi4, lo4;
        unsigned short* hp = (unsigned short*)&hi4;
        unsigned short* lp = (unsigned short*)&lo4;
        #pragma unroll
        for (int j = 0; j < 4; ++j) {
            unsigned short h = f2bs(vv[j]);
            hp[j] = h;
            lp[j] = f2bs(vv[j] - bf2f(h));
        }
        *(ushort4*)&Ah[rr][cc] = hi4;
        *(ushort4*)&Al[rr][cc] = lo4;
        ushort4 wb4;
        unsigned short* wp = (unsigned short*)&wb4;
        if (wbf) {
            wb4 = *(const ushort4*)((const unsigned short*)W + (size_t)(bn + rr) * 16 + cc);
        } else {
            float4 wv = *(const float4*)((const float*)W + (size_t)(bn + rr) * 16 + cc);
            wp[0] = f2bs(wv.x); wp[1] = f2bs(wv.y); wp[2] = f2bs(wv.z); wp[3] = f2bs(wv.w);
        }
        *(ushort4*)&Wb[rr][cc] = wb4;
    }
    __syncthreads();

    const int l = tid & 63, wid = tid >> 6;
    const int wr = wid >> 1, wc = wid & 1;
    const int lr = l & 15, lq = l >> 4;

    f32x4 acc[2][2] = {};
    bf16x8 ah[2], al8[2], wb8[2];
    #pragma unroll
    for (int i = 0; i < 2; ++i) { ah[i] = bf16x8{}; al8[i] = bf16x8{}; wb8[i] = bf16x8{}; }
    if (lq < 2) {
        #pragma unroll
        for (int i = 0; i < 2; ++i) {
            ah[i]  = *(const bf16x8*)&Ah[wr * 32 + i * 16 + lr][lq * 8];
            al8[i] = *(const bf16x8*)&Al[wr * 32 + i * 16 + lr][lq * 8];
            wb8[i] = *(const bf16x8*)&Wb[wc * 32 + i * 16 + lr][lq * 8];
        }
    }
    #pragma unroll
    for (int i = 0; i < 2; ++i)
        #pragma unroll
        for (int j = 0; j < 2; ++j) {
            acc[i][j] = __builtin_amdgcn_mfma_f32_16x16x32_bf16(ah[i],  wb8[j], acc[i][j], 0, 0, 0);
            acc[i][j] = __builtin_amdgcn_mfma_f32_16x16x32_bf16(al8[i], wb8[j], acc[i][j], 0, 0, 0);
        }

    #pragma unroll
    for (int i = 0; i < 2; ++i) {
        #pragma unroll
        for (int j = 0; j < 2; ++j) {
            const int col = bn + wc * 32 + j * 16 + lr;
            #pragma unroll
            for (int e = 0; e < 4; ++e) {
                const int row = bm + wr * 32 + i * 16 + lq * 4 + e;
                float t = acc[i][j][e] + ldw(bias, col, wbf);
                t = (t > 20.f) ? t : log1pf(__expf(t));
                Cout[(size_t)row * 256 + col] = f2bs(t);
            }
        }
    }
}

// ------------------------------------------------- depthwise conv3 + SiLU (8 rows/block, 8 ch/thread, reg weights)
__global__ __launch_bounds__(256) void conv_silu_kernel(
    const unsigned short* __restrict__ xz,
    const void* __restrict__ wx, const void* __restrict__ wz,
    unsigned short* __restrict__ u, unsigned short* __restrict__ z,
    const int* __restrict__ flagp)
{
    const bool wbf = (*flagp != 0);
    int sub = threadIdx.x >> 5;
    int cb = (threadIdx.x & 31) * 8;
    int bl = blockIdx.x * 8 + sub;
    int l = bl % L_;
    const unsigned short* r = xz + (size_t)bl * 512;
    bool hasm = (l > 0), hasp = (l < L_ - 1);

    float wxa[24], wza[24];
    if (wbf) {
        const unsigned short* px = (const unsigned short*)wx + 3 * cb;
        const unsigned short* pz = (const unsigned short*)wz + 3 * cb;
        #pragma unroll
        for (int t = 0; t < 3; ++t) {
            cvt4(*(const ushort4*)(px + t * 8), &wxa[t * 8]);
            cvt4(*(const ushort4*)(px + t * 8 + 4), &wxa[t * 8 + 4]);
            cvt4(*(const ushort4*)(pz + t * 8), &wza[t * 8]);
            cvt4(*(const ushort4*)(pz + t * 8 + 4), &wza[t * 8 + 4]);
        }
    } else {
        const float* px = (const float*)wx + 3 * cb;
        const float* pz = (const float*)wz + 3 * cb;
        #pragma unroll
        for (int t = 0; t < 6; ++t) {
            *(float4*)&wxa[t * 4] = *(const float4*)(px + t * 4);
            *(float4*)&wza[t * 4] = *(const float4*)(pz + t * 4);
        }
    }

    float xm[8], xc[8], xp[8];
    cvt8g(r + cb - 512, hasm, xm);
    cvt8g(r + cb,       true, xc);
    cvt8g(r + cb + 512, hasp, xp);
    ushort4 o0, o1;
    {
        unsigned short* op = (unsigned short*)&o0;
        unsigned short* op1 = (unsigned short*)&o1;
        #pragma unroll
        for (int j = 0; j < 8; ++j) {
            float v = xm[j] * wxa[3 * j] + xc[j] * wxa[3 * j + 1] + xp[j] * wxa[3 * j + 2];
            v = v / (1.f + __expf(-v));
            if (j < 4) op[j] = f2bs(v); else op1[j - 4] = f2bs(v);
        }
    }
    *(ushort4*)(u + (size_t)bl * 256 + cb) = o0;
    *(ushort4*)(u + (size_t)bl * 256 + cb + 4) = o1;

    cvt8g(r + cb - 256,  hasm, xm);
    cvt8g(r + 256 + cb,  true, xc);
    cvt8g(r + 768 + cb,  hasp, xp);
    {
        unsigned short* op = (unsigned short*)&o0;
        unsigned short* op1 = (unsigned short*)&o1;
        #pragma unroll
        for (int j = 0; j < 8; ++j) {
            float v = xm[j] * wza[3 * j] + xc[j] * wza[3 * j + 1] + xp[j] * wza[3 * j + 2];
            v = v / (1.f + __expf(-v));
            if (j < 4) op[j] = f2bs(v); else op1[j - 4] = f2bs(v);
        }
    }
    *(ushort4*)(z + (size_t)bl * 256 + cb) = o0;
    *(ushort4*)(z + (size_t)bl * 256 + cb + 4) = o1;
}

// ------------------------------------------------- selective scan (transposed LDS, b128-batched)
__global__ __launch_bounds__(256) void scan_a_kernel(
    const unsigned short* __restrict__ delta, const unsigned short* __restrict__ u,
    const float* __restrict__ xdbl, const void* __restrict__ A_log,
    float* __restrict__ hend, float* __restrict__ dsum, const int* __restrict__ flagp)
{
    const bool wbf = (*flagp != 0);
    int blk = blockIdx.x;
    int b = blk / (NCH * 16);
    int rem = blk % (NCH * 16);
    int c = rem / 16, db = rem % 16;

    __shared__ unsigned int sduT[16][68];   // [d-group][t2], packed delta|u
    __shared__ float sBT[16][68];           // [n][t2]

    const unsigned short* dp = delta + (size_t)b * L_ * 256;
    const unsigned short* up = u     + (size_t)b * L_ * 256;
    const float* xd = xdbl + (size_t)b * L_ * 48;

    int r = threadIdx.x >> 2, q = (threadIdx.x & 3) * 4;
    int lrow = c * 64 + r;
    {
        ushort4 dv = *(const ushort4*)(dp + (size_t)lrow * 256 + db * 16 + q);
        ushort4 uv = *(const ushort4*)(up + (size_t)lrow * 256 + db * 16 + q);
        sduT[q + 0][r] = (unsigned)dv.x | ((unsigned)uv.x << 16);
        sduT[q + 1][r] = (unsigned)dv.y | ((unsigned)uv.y << 16);
        sduT[q + 2][r] = (unsigned)dv.z | ((unsigned)uv.z << 16);
        sduT[q + 3][r] = (unsigned)dv.w | ((unsigned)uv.w << 16);
        float4 Bv = *(const float4*)(xd + (size_t)lrow * 48 + 16 + q);
        sBT[q + 0][r] = Bv.x; sBT[q + 1][r] = Bv.y;
        sBT[q + 2][r] = Bv.z; sBT[q + 3][r] = Bv.w;
    }
    __syncthreads();

    int g = threadIdx.x >> 4, n = threadIdx.x & 15;
    int d = db * 16 + g;
    float An2 = -__expf(ldw(A_log, d * 16 + n, wbf)) * 1.44269504088896f;
    float h = 0.f, s = 0.f;
    #pragma unroll 4
    for (int tb = 0; tb < 16; ++tb) {
        uint4 du4 = *(const uint4*)&sduT[g][tb * 4];
        float4 B4 = *(const float4*)&sBT[n][tb * 4];
        #pragma unroll
        for (int j = 0; j < 4; ++j) {
            unsigned du = (j == 0) ? du4.x : (j == 1) ? du4.y : (j == 2) ? du4.z : du4.w;
            float Bn = (j == 0) ? B4.x : (j == 1) ? B4.y : (j == 2) ? B4.z : B4.w;
            float ds = __uint_as_float(du << 16);
            float ut = __uint_as_float(du & 0xFFFF0000u);
            float e = exp2f(ds * An2);
            h = fmaf(e, h, ds * ut * Bn);
            s += ds;
        }
    }
    size_t pair = (size_t)b * 256 + d;
    hend[(pair * NCH + c) * 16 + n] = h;
    if (n == 0) dsum[pair * NCH + c] = s;
}

// ------------------------------------------------- combine (256 blocks x 64 thr, 7x7 prefetch)
__global__ __launch_bounds__(64) void scan_b_kernel(
    const void* __restrict__ A_log, float* __restrict__ hend,
    const float* __restrict__ dsum, const int* __restrict__ flagp)
{
    const bool wbf = (*flagp != 0);
    int gid = blockIdx.x * 64 + threadIdx.x;   // 16384
    int pair = gid >> 4, n = gid & 15;
    int d = pair & 255;
    float An = -__expf(ldw(A_log, d * 16 + n, wbf));
    float H = 0.f;
    #pragma unroll 1
    for (int c0 = 0; c0 < NCH; c0 += 7) {
        float he[7], dd[7];
        #pragma unroll
        for (int j = 0; j < 7; ++j) {
            he[j] = hend[((size_t)pair * NCH + c0 + j) * 16 + n];
            dd[j] = dsum[(size_t)pair * NCH + c0 + j];
        }
        #pragma unroll
        for (int j = 0; j < 7; ++j) {
            hend[((size_t)pair * NCH + c0 + j) * 16 + n] = H;
            H = __expf(An * dd[j]) * H + he[j];
        }
    }
}

__global__ __launch_bounds__(256) void scan_c_kernel(
    const unsigned short* __restrict__ delta, const unsigned short* __restrict__ u,
    const float* __restrict__ xdbl, const void* __restrict__ A_log,
    const void* __restrict__ Dp, const float* __restrict__ hinit,
    unsigned short* __restrict__ y, const int* __restrict__ flagp)
{
    const bool wbf = (*flagp != 0);
    int blk = blockIdx.x;
    int b = blk / (NCH * 16);
    int rem = blk % (NCH * 16);
    int c = rem / 16, db = rem % 16;

    __shared__ unsigned int sduT[16][68];    // [d-group][t2]
    __shared__ float sBCT[16][132];          // [n][t2*2 + {B,C}]
    __shared__ float sypT[16][4][68];        // [d-group][quad][t2]
    __shared__ unsigned short sy[64][16];

    const unsigned short* dp = delta + (size_t)b * L_ * 256;
    const unsigned short* up = u     + (size_t)b * L_ * 256;
    const float* xd = xdbl + (size_t)b * L_ * 48;

    int r = threadIdx.x >> 2, q = (threadIdx.x & 3) * 4;
    int lrow = c * 64 + r;
    {
        ushort4 dv = *(const ushort4*)(dp + (size_t)lrow * 256 + db * 16 + q);
        ushort4 uv = *(const ushort4*)(up + (size_t)lrow * 256 + db * 16 + q);
        sduT[q + 0][r] = (unsigned)dv.x | ((unsigned)uv.x << 16);
        sduT[q + 1][r] = (unsigned)dv.y | ((unsigned)uv.y << 16);
        sduT[q + 2][r] = (unsigned)dv.z | ((unsigned)uv.z << 16);
        sduT[q + 3][r] = (unsigned)dv.w | ((unsigned)uv.w << 16);
        float4 Bv = *(const float4*)(xd + (size_t)lrow * 48 + 16 + q);
        float4 Cv = *(const float4*)(xd + (size_t)lrow * 48 + 32 + q);
        float2 t0; t0.x = Bv.x; t0.y = Cv.x; *(float2*)&sBCT[q + 0][r * 2] = t0;
        float2 t1; t1.x = Bv.y; t1.y = Cv.y; *(float2*)&sBCT[q + 1][r * 2] = t1;
        float2 t2; t2.x = Bv.z; t2.y = Cv.z; *(float2*)&sBCT[q + 2][r * 2] = t2;
        float2 t3; t3.x = Bv.w; t3.y = Cv.w; *(float2*)&sBCT[q + 3][r * 2] = t3;
    }
    __syncthreads();

    int g = threadIdx.x >> 4, n = threadIdx.x & 15;
    int d = db * 16 + g;
    float An2 = -__expf(ldw(A_log, d * 16 + n, wbf)) * 1.44269504088896f;
    size_t pair = (size_t)b * 256 + d;
    float h = hinit[(pair * NCH + c) * 16 + n];
    const bool wlane = ((n & 3) == 0);
    const int p = n >> 2;
    #pragma unroll 4
    for (int tb = 0; tb < 16; ++tb) {
        uint4 du4 = *(const uint4*)&sduT[g][tb * 4];
        float4 bc01 = *(const float4*)&sBCT[n][tb * 8];
        float4 bc23 = *(const float4*)&sBCT[n][tb * 8 + 4];
        float yp4[4];
        #pragma unroll
        for (int j = 0; j < 4; ++j) {
            unsigned du = (j == 0) ? du4.x : (j == 1) ? du4.y : (j == 2) ? du4.z : du4.w;
            float Bn = (j == 0) ? bc01.x : (j == 1) ? bc01.z : (j == 2) ? bc23.x : bc23.z;
            float Cn = (j == 0) ? bc01.y : (j == 1) ? bc01.w : (j == 2) ? bc23.y : bc23.w;
            float ds = __uint_as_float(du << 16);
            float ut = __uint_as_float(du & 0xFFFF0000u);
            float e = exp2f(ds * An2);
            h = fmaf(e, h, ds * ut * Bn);
            float yp = h * Cn;
            yp = dpp_add_xor1(yp);
            yp = dpp_add_xor2(yp);
            yp4[j] = yp;
        }
        if (wlane) *(float4*)&sypT[g][p][tb * 4] = *(float4*)yp4;
    }
    __syncthreads();

    #pragma unroll
    for (int cc = 0; cc < 4; ++cc) {
        int cell = threadIdx.x + cc * 256;
        int t2 = cell >> 4, gg = cell & 15;
        float sum = sypT[gg][0][t2] + sypT[gg][1][t2] + sypT[gg][2][t2] + sypT[gg][3][t2];
        unsigned du = sduT[gg][t2];
        float ut = __uint_as_float(du & 0xFFFF0000u);
        float Dd = ldw(Dp, db * 16 + gg, wbf);
        sy[t2][gg] = f2bs(sum + ut * Dd);
    }
    __syncthreads();
    *(ushort4*)(y + ((size_t)b * L_ + c * 64 + r) * 256 + db * 16 + q) = *(ushort4*)&sy[r][q];
}

// ------------------------------------------------- launch
extern "C" void kernel_launch(void* const* d_in, const int* in_sizes, int n_in,
                              void* d_out, int out_size, void* d_ws, size_t ws_size,
                              hipStream_t stream) {
    const void* x         = d_in[0];
    const void* ln1_g     = d_in[1];
    const void* ln1_b     = d_in[2];
    const void* ln2_g     = d_in[3];
    const void* ln2_b     = d_in[4];
    const void* in_proj_w = d_in[5];
    const void* conv_x_w  = d_in[6];
    const void* conv_z_w  = d_in[7];
    const void* x_proj_w  = d_in[8];
    const void* dt_proj_w = d_in[9];
    const void* dt_proj_b = d_in[10];
    const void* A_log     = d_in[11];
    const void* Dp        = d_in[12];
    const void* out_proj_w= d_in[13];
    const void* mlp_w1    = d_in[14];
    const void* mlp_b1    = d_in[15];
    const void* mlp_w2    = d_in[16];
    const void* mlp_b2    = d_in[17];

    float* ws = (float*)d_ws;
    unsigned short* xz    = (unsigned short*)(ws);
    unsigned short* delta = (unsigned short*)(ws);
    unsigned short* yb    = (unsigned short*)(ws + 1605632);
    float*          xdbl  = ws + 3211264;
    float*          hend  = ws + 3813376;
    float*          dsum  = ws + 4616192;
    unsigned short* hmid  = (unsigned short*)(ws);
    unsigned short* ub    = (unsigned short*)(ws + 6422528);
    unsigned short* xres  = (unsigned short*)(ws + 6422528);
    unsigned short* xnb   = (unsigned short*)(ws + 8028160);  // xn / z / xn2
    int*            flag  = (int*)(ws + 9633792);

    dim3 blk(256);
    const int KNOSPLIT = 1 << 30;

    // 0. dtype detection -> flag
    detect_kernel<<<1, blk, 0, stream>>>((const unsigned int*)x, flag);

    // 1. LN1: x(dual) -> xn (bf16)
    ln_kernel<<<M_ / 4, blk, 0, stream>>>(x, -1, ln1_g, ln1_b, xnb, flag);

    // 2. in_proj (MFMA): xn x W(512,256)^T -> xz (M,512) bf16
    mgemm_kernel<EPI_NONE><<<dim3(8, 196), blk, 0, stream>>>(
        xnb, nullptr, KNOSPLIT, in_proj_w, xz, 512, 256, 256, 512, nullptr, nullptr, nullptr, flag);

    // 3. conv+silu: xz -> u (bf16), z (bf16 -> xnb, xn dead)
    conv_silu_kernel<<<M_ / 8, blk, 0, stream>>>(xz, conv_x_w, conv_z_w, ub, xnb, flag);

    // 4. x_proj (MFMA): u x W(48,256)^T -> xdbl (M,48) fp32
    xproj_kernel<<<dim3(1, 196), blk, 0, stream>>>(ub, x_proj_w, xdbl, flag);

    // 5. dt_proj (MFMA hi/lo) + softplus: xdbl[:,:16] x W(256,16)^T -> delta (bf16)
    dtgemm_kernel<<<dim3(4, 196), blk, 0, stream>>>(xdbl, dt_proj_w, delta, dt_proj_b, flag);

    // 6-8. selective scan
    scan_a_kernel<<<B_ * NCH * 16, blk, 0, stream>>>(delta, ub, xdbl, A_log, hend, dsum, flag);
    scan_b_kernel<<<256, dim3(64), 0, stream>>>(A_log, hend, dsum, flag);
    scan_c_kernel<<<B_ * NCH * 16, blk, 0, stream>>>(delta, ub, xdbl, A_log, Dp, hend, yb, flag);

    // 9. out_proj + residual (MFMA, split A = [y | z]) -> xres bf16
    mgemm_kernel<EPI_RES><<<dim3(4, 196), blk, 0, stream>>>(
        yb, xnb, 256, out_proj_w, xres, 256, 512, 256, 256, nullptr, x, nullptr, flag);

    // 10. LN2: xres -> xn2 (bf16 -> xnb, z dead)
    ln_kernel<<<M_ / 4, blk, 0, stream>>>(xres, 1, ln2_g, ln2_b, xnb, flag);

    // 11. MLP1 + bias + GELU (MFMA): xn2 x W(1024,256)^T -> hmid bf16
    mgemm_kernel<EPI_GELU><<<dim3(16, 196), blk, 0, stream>>>(
        xnb, nullptr, KNOSPLIT, mlp_w1, hmid, 1024, 256, 256, 1024, mlp_b1, nullptr, nullptr, flag);

    // 12. MLP2 + bias + residual (MFMA) -> d_out (dtype per flag)
    mgemm_kernel<EPI_OUT><<<dim3(4, 196), blk, 0, stream>>>(
        hmid, nullptr, KNOSPLIT, mlp_w2, d_out, 256, 1024, 1024, 256, mlp_b2, nullptr, xres, flag);
}